// Round 11
// baseline (754.412 us; speedup 1.0000x reference)
//
#include <hip/hip_runtime.h>
#include <math.h>

// Problem constants (fixed by reference setup)
#define NN 50000
#define EE 400000
#define CINV 32
#define KKEEP 25000          // ceil(0.5*N)
#define SEQL 5
#define HASH_BITS 20
#define HASH_SIZE (1u<<HASH_BITS)
#define HASH_MASK (HASH_SIZE-1u)
#define HEMPTY 0xFFFFFFFFu
#define PSB 196              // ceil(NN/256)

typedef float vf4 __attribute__((ext_vector_type(4)));

__device__ __forceinline__ float sigm(float x){ return __builtin_amdgcn_rcpf(1.f+__expf(-x)); }
__device__ __forceinline__ float ftanh(float x){ return 1.f - 2.f*__builtin_amdgcn_rcpf(1.f+__expf(2.f*x)); }

// ---------------- merged init (+ LSTM weight prep) ----------------
__global__ void k_init(uint2* __restrict__ hash, unsigned* __restrict__ hist,
                       int* __restrict__ degcnt, int* __restrict__ diagint,
                       int* __restrict__ fillc, int* __restrict__ minv,
                       unsigned* scal, unsigned long long* selp,
                       const float* __restrict__ w0, const float* __restrict__ b0i,
                       const float* __restrict__ b0h, const float* __restrict__ wf,
                       const float* __restrict__ bfi, const float* __restrict__ bfh,
                       float* __restrict__ WT0, float* __restrict__ WTf,
                       float* __restrict__ bs0, float* __restrict__ bsf){
  int i = blockIdx.x*256 + threadIdx.x;
  if (i < (int)HASH_SIZE) hash[i] = make_uint2(HEMPTY, 0u);
  if (i < 4*65536) hist[i] = 0u;
  if (i < NN){ degcnt[i]=0; diagint[i]=0; fillc[i]=0; minv[i]=-1; }
  if (i < 256*64){
    int g = i>>6, k = i&63;
    WT0[k*256+g] = w0[i];
    WTf[k*256+g] = wf[i];
  }
  if (i < 256){ bs0[i]=b0i[i]+b0h[i]; bsf[i]=bfi[i]+bfh[i]; }
  if (i == 0){ scal[0]=0u; scal[1]=0u; scal[3]=KKEEP; selp[0]=0ull; }
}

// ---------------- phase2: degcnt + hash build + mask detect + GCN0 matmul ----------------
__global__ void k_phase2(const int* __restrict__ row, const int* __restrict__ col,
                         const int* __restrict__ mp, int* __restrict__ degcnt,
                         uint2* __restrict__ tab, unsigned* scal,
                         const float* __restrict__ X, const float* __restrict__ W,
                         float* __restrict__ Y){
  int idx = blockIdx.x*256 + threadIdx.x;
  if (idx < EE){
    int c = col[idx];
    atomicAdd(&degcnt[c], 1);
    unsigned key = (unsigned)row[idx]*50000u + (unsigned)c;
    unsigned h = (key*2654435761u) >> (32-HASH_BITS);
    for(;;){
      unsigned old = atomicCAS(&tab[h].x, HEMPTY, key);
      if (old==HEMPTY || old==key){ atomicAdd(&tab[h].y, 1u); break; }
      h = (h+1)&HASH_MASK;
    }
  }
  if (idx < NN/4){ if ((unsigned)mp[idx] > 1u) atomicOr(&scal[1], 1u); }
  if (idx < NN*16){
    int i = idx>>4, fq = idx&15;
    const vf4* X4 = (const vf4*)&X[i*CINV];
    const vf4* W4 = (const vf4*)W;
    vf4 acc = {0.f,0.f,0.f,0.f};
    #pragma unroll
    for (int kq=0;kq<CINV/4;kq++){
      vf4 xv = X4[kq];
      #pragma unroll
      for (int u=0;u<4;u++) acc += xv[u] * W4[(kq*4+u)*16+fq];
    }
    ((vf4*)Y)[i*16+fq] = acc;
  }
}

// ---------------- prefix sum (indptr) + dinv0 ----------------
__global__ void k_psum1(const int* __restrict__ deg, int* __restrict__ part,
                        int* __restrict__ bsum, float* __restrict__ dinv){
  __shared__ int sc[256];
  int b = blockIdx.x, t = threadIdx.x, i = b*256+t;
  int v = (i<NN) ? deg[i] : 0;
  if (i < NN) dinv[i] = rsqrtf((float)v + 2.0f);
  sc[t] = v; __syncthreads();
  for (int o=1;o<256;o<<=1){
    int x = (t>=o) ? sc[t-o] : 0;
    __syncthreads();
    sc[t] += x;
    __syncthreads();
  }
  if (i < NN) part[i] = sc[t]-v;
  if (t == 255) bsum[b] = sc[255];
}
// psum3 with per-block redundant scan of bsum
__global__ void k_psum3(const int* __restrict__ part, const int* __restrict__ bsum,
                        int* __restrict__ indptr){
  __shared__ int sc[256];
  int t = threadIdx.x;
  int v = (t<PSB) ? bsum[t] : 0;
  sc[t] = v; __syncthreads();
  for (int o=1;o<256;o<<=1){
    int x = (t>=o) ? sc[t-o] : 0;
    __syncthreads();
    sc[t] += x;
    __syncthreads();
  }
  int bb = blockIdx.x;
  int ex = sc[bb] - ((bb<PSB) ? bsum[bb] : 0);
  int i = bb*256 + t;
  if (i < NN) indptr[i] = part[i] + ex;
  if (i == 0) indptr[NN] = EE;
}

// ---------------- csr fill + A^2 diag + mask compact ----------------
__global__ void k_phase4(const int* __restrict__ row, const int* __restrict__ col,
                         const int* __restrict__ indptr, int* __restrict__ fillc,
                         int* __restrict__ csr_r, const uint2* __restrict__ tab,
                         int* __restrict__ diagint, const void* __restrict__ mp,
                         unsigned* scal, int* __restrict__ mlist, int* __restrict__ minv){
  int idx = blockIdx.x*256 + threadIdx.x;
  if (idx < EE){
    int r = row[idx], c = col[idx];
    int pos = indptr[c] + atomicAdd(&fillc[c], 1);
    csr_r[pos] = r;
    unsigned rkey = (unsigned)c*50000u + (unsigned)r;
    unsigned h = (rkey*2654435761u) >> (32-HASH_BITS);
    for(;;){
      unsigned kk = tab[h].x;
      if (kk==rkey){ atomicAdd(&diagint[r], (int)tab[h].y); break; }
      if (kk==HEMPTY) break;
      h = (h+1)&HASH_MASK;
    }
  } else {
    int i = idx - EE;
    if (i < NN){
      int mv = scal[1] ? (int)((const unsigned char*)mp)[i] : ((const int*)mp)[i];
      if (mv){ int p = (int)atomicAdd(&scal[0], 1u); mlist[p] = i; minv[i] = p; }
    }
  }
}

// ---------------- remaining matmul (up-GCN input) ----------------
__global__ void k_mm64v(const float* __restrict__ X, const float* __restrict__ W, float* __restrict__ Y){
  int idx = blockIdx.x*256 + threadIdx.x;
  if (idx >= NN*16) return;
  int i = idx>>4, fq = idx&15;
  const vf4* X4 = (const vf4*)&X[i*64];
  const vf4* W4 = (const vf4*)W;
  vf4 acc = {0.f,0.f,0.f,0.f};
  #pragma unroll
  for (int kq=0;kq<16;kq++){
    vf4 xv = X4[kq];
    #pragma unroll
    for (int u=0;u<4;u++) acc += xv[u] * W4[(kq*4+u)*16+fq];
  }
  ((vf4*)Y)[i*16+fq] = acc;
}

// ---------------- CSR gather GCN kernels (wave per node, shuffle-pipelined) ----------------
__global__ void g_gcn0(const int* __restrict__ indptr, const int* __restrict__ csr_r,
                       const float* __restrict__ dinv, const float* __restrict__ H,
                       const float* __restrict__ b, const float* __restrict__ pw,
                       float* __restrict__ out, unsigned long long* __restrict__ keys,
                       float* __restrict__ score, unsigned* __restrict__ hist){
  int node = blockIdx.x*4 + (threadIdx.x>>6), lane = threadIdx.x&63;
  if (node >= NN) return;
  int s = __builtin_amdgcn_readfirstlane(indptr[node]);
  int e = __builtin_amdgcn_readfirstlane(indptr[node+1]);
  int deg = e - s;
  float a0=0.f,a1=0.f,a2=0.f,a3=0.f;
  for (int base=0; base<deg; base+=64){
    int take = min(64, deg-base);
    bool act = lane < take;
    int ii = act ? csr_r[s+base+lane] : 0;
    float dv = act ? dinv[ii] : 0.f;
    int j=0;
    for (; j+4<=take; j+=4){
      int r0=__shfl(ii,j,64), r1=__shfl(ii,j+1,64), r2=__shfl(ii,j+2,64), r3=__shfl(ii,j+3,64);
      float d0=__shfl(dv,j,64), d1=__shfl(dv,j+1,64), d2=__shfl(dv,j+2,64), d3=__shfl(dv,j+3,64);
      a0 += d0*H[(size_t)r0*64+lane];
      a1 += d1*H[(size_t)r1*64+lane];
      a2 += d2*H[(size_t)r2*64+lane];
      a3 += d3*H[(size_t)r3*64+lane];
    }
    for (; j<take; j++){
      int r0=__shfl(ii,j,64); float d0=__shfl(dv,j,64);
      a0 += d0*H[(size_t)r0*64+lane];
    }
  }
  float acc = (a0+a1)+(a2+a3);
  float di = dinv[node];
  float v = di*acc + 2.f*di*di*H[(size_t)node*64+lane] + b[lane];
  float x1v = fmaxf(v, 0.f);
  out[(size_t)node*64+lane] = x1v;
  // fused TopK score: s = tanh((x1 . pw)/||pw||)
  float pv = pw[lane];
  float nq = pv*pv;
  float dq = x1v*pv;
  for (int o=32;o;o>>=1){ nq += __shfl_down(nq, o, 64); dq += __shfl_down(dq, o, 64); }
  if (lane==0){
    float sv = tanhf(dq / sqrtf(nq));
    sv = sv + 0.0f;               // canonicalize -0 -> +0
    score[node] = sv;
    unsigned u = __float_as_uint(sv);
    unsigned asc = (u>>31) ? ~u : (u | 0x80000000u);
    unsigned desc = ~asc;
    keys[node] = (((unsigned long long)desc)<<32) | (unsigned)node;
    atomicAdd(&hist[desc>>16], 1u);      // radix round-0 histogram
  }
}
__global__ void g_t2(const int* __restrict__ indptr, const int* __restrict__ csr_r,
                     const float* __restrict__ dinv1, const float* __restrict__ hp,
                     float* __restrict__ t2){
  int node = blockIdx.x*4 + (threadIdx.x>>6), lane = threadIdx.x&63;
  if (node >= NN) return;
  int s = __builtin_amdgcn_readfirstlane(indptr[node]);
  int e = __builtin_amdgcn_readfirstlane(indptr[node+1]);
  int deg = e - s;
  float a0 = dinv1[node]*hp[(size_t)node*64+lane];   // self loop
  float a1 = 0.f;
  for (int base=0; base<deg; base+=64){
    int take = min(64, deg-base);
    bool act = lane < take;
    int ii = act ? csr_r[s+base+lane] : 0;
    float dv = act ? dinv1[ii] : 0.f;
    int j=0;
    for (; j+2<=take; j+=2){
      float d0=__shfl(dv,j,64), d1=__shfl(dv,j+1,64);
      int r0=__shfl(ii,j,64), r1=__shfl(ii,j+1,64);
      if (d0!=0.f) a0 += d0*hp[(size_t)r0*64+lane];
      if (d1!=0.f) a1 += d1*hp[(size_t)r1*64+lane];
    }
    for (; j<take; j++){
      float d0=__shfl(dv,j,64); int r0=__shfl(ii,j,64);
      if (d0!=0.f) a0 += d0*hp[(size_t)r0*64+lane];
    }
  }
  t2[(size_t)node*64+lane] = a0+a1;
}
// D[i] = (masked ? H0[minv[i]] : C[i]) + (kept ? relu(x2_i) : 0)
__global__ void g_agg2y(const int* __restrict__ indptr, const int* __restrict__ csr_r,
                        const float* __restrict__ t2, const float* __restrict__ hp,
                        const float* __restrict__ dinv1, const int* __restrict__ diagint,
                        const int* __restrict__ kp, const float* __restrict__ b1,
                        const float* __restrict__ C, const float* __restrict__ Hbuf,
                        const int* __restrict__ minv, float* __restrict__ D){
  int node = blockIdx.x*4 + (threadIdx.x>>6), lane = threadIdx.x&63;
  if (node >= NN) return;
  int mv = minv[node];
  float base = (mv >= 0) ? Hbuf[(size_t)mv*64+lane] : C[(size_t)node*64+lane];
  float add = 0.f;
  if (kp[node]){
    int s = __builtin_amdgcn_readfirstlane(indptr[node]);
    int e = __builtin_amdgcn_readfirstlane(indptr[node+1]);
    int deg = e - s;
    float a0 = t2[(size_t)node*64+lane];             // self loop
    float a1=0.f,a2=0.f,a3=0.f;
    for (int bs2=0; bs2<deg; bs2+=64){
      int take = min(64, deg-bs2);
      bool act = lane < take;
      int ii = act ? csr_r[s+bs2+lane] : 0;
      int j=0;
      for (; j+4<=take; j+=4){
        int r0=__shfl(ii,j,64), r1=__shfl(ii,j+1,64), r2=__shfl(ii,j+2,64), r3=__shfl(ii,j+3,64);
        a0 += t2[(size_t)r0*64+lane];
        a1 += t2[(size_t)r1*64+lane];
        a2 += t2[(size_t)r2*64+lane];
        a3 += t2[(size_t)r3*64+lane];
      }
      for (; j<take; j++){
        int r0=__shfl(ii,j,64);
        a0 += t2[(size_t)r0*64+lane];
      }
    }
    float acc = (a0+a1)+(a2+a3);
    float di = dinv1[node], hv = hp[(size_t)node*64+lane];
    float diag = (float)(diagint[node] + 1);
    float v = di*(acc - diag*di*hv) + 2.f*di*di*hv + b1[lane];
    add = fmaxf(v, 0.f);
  }
  D[(size_t)node*64+lane] = base + add;
}
__global__ void g_up(const int* __restrict__ indptr, const int* __restrict__ csr_r,
                     const float* __restrict__ dinv, const float* __restrict__ H,
                     const float* __restrict__ b, float* __restrict__ xo, float* __restrict__ out){
  int node = blockIdx.x*4 + (threadIdx.x>>6), lane = threadIdx.x&63;
  if (node >= NN) return;
  int s = __builtin_amdgcn_readfirstlane(indptr[node]);
  int e = __builtin_amdgcn_readfirstlane(indptr[node+1]);
  int deg = e - s;
  float a0=0.f,a1=0.f,a2=0.f,a3=0.f;
  for (int base=0; base<deg; base+=64){
    int take = min(64, deg-base);
    bool act = lane < take;
    int ii = act ? csr_r[s+base+lane] : 0;
    float dv = act ? dinv[ii] : 0.f;
    int j=0;
    for (; j+4<=take; j+=4){
      int r0=__shfl(ii,j,64), r1=__shfl(ii,j+1,64), r2=__shfl(ii,j+2,64), r3=__shfl(ii,j+3,64);
      float d0=__shfl(dv,j,64), d1=__shfl(dv,j+1,64), d2=__shfl(dv,j+2,64), d3=__shfl(dv,j+3,64);
      a0 += d0*H[(size_t)r0*64+lane];
      a1 += d1*H[(size_t)r1*64+lane];
      a2 += d2*H[(size_t)r2*64+lane];
      a3 += d3*H[(size_t)r3*64+lane];
    }
    for (; j<take; j++){
      int r0=__shfl(ii,j,64); float d0=__shfl(dv,j,64);
      a0 += d0*H[(size_t)r0*64+lane];
    }
  }
  float acc = (a0+a1)+(a2+a3);
  float di = dinv[node];
  float v = di*acc + 2.f*di*di*H[(size_t)node*64+lane] + b[lane];
  xo[(size_t)node*64+lane] = v; out[(size_t)node*64+lane] = v;
}

// ---------------- fused TopK radix select: all 4 rounds in ONE kernel ----------------
// Single block. Round 0 reads the g_gcn0-prebuilt global hist slab 0 (cross-
// kernel, safe). Rounds 1-3 build their slab via global atomics (slabs are
// first-touched-by-atomic inside this kernel, so the post-barrier plain loads
// cannot hit stale L1) and pick. Replaces 4x k_pick + 3x k_hist launches.
__global__ __launch_bounds__(256) void k_radix(const unsigned long long* __restrict__ keys,
        unsigned* __restrict__ hist, unsigned long long* __restrict__ selp,
        const unsigned* __restrict__ scal){
  __shared__ unsigned csum[256];
  __shared__ unsigned bins[256];
  __shared__ int schunk;
  __shared__ unsigned long long spfx;
  __shared__ unsigned srem;
  int t = threadIdx.x;
  if (t==0){ srem = scal[3]; spfx = 0ull; }
  __syncthreads();
  for (int rnd=0; rnd<4; rnd++){
    unsigned* h = hist + rnd*65536;
    if (rnd > 0){
      int shift = 48 - 16*rnd;
      unsigned long long pfx = spfx;
      for (int i=t; i<NN; i+=256){
        unsigned long long key = keys[i];
        if ((key>>(shift+16)) == pfx)
          atomicAdd(&h[(unsigned)((key>>shift)&0xFFFFull)], 1u);
      }
      __syncthreads();
    }
    const uint4* h4 = (const uint4*)(h + t*256);
    unsigned s = 0;
    #pragma unroll 8
    for (int j=0;j<64;j++){ uint4 v = h4[j]; s += v.x+v.y+v.z+v.w; }
    csum[t] = s;
    __syncthreads();
    if (t==0){
      unsigned rem = srem;
      int chunk = 255;
      for (int c2=0;c2<256;c2++){ unsigned cc=csum[c2]; if (rem>cc) rem-=cc; else { chunk=c2; break; } }
      schunk = chunk; srem = rem;
    }
    __syncthreads();
    bins[t] = h[schunk*256 + t];
    __syncthreads();
    if (t==0){
      unsigned rem = srem;
      int bin = schunk*256 + 255;
      for (int b=0;b<256;b++){ unsigned hv=bins[b]; if (rem>hv) rem-=hv; else { bin = schunk*256 + b; break; } }
      spfx = (spfx<<16) | (unsigned long long)(unsigned)bin;
      srem = rem;
    }
    __syncthreads();
  }
  if (t==0) selp[0] = spfx;
}

// pooled degree pass 1 (CSR gather): kp[i]; ts[i] = sum_{r->i} kp[r] + kp[i]
__global__ void k_tsg(const int* __restrict__ indptr, const int* __restrict__ csr_r,
                      const unsigned long long* __restrict__ keys,
                      const unsigned long long* __restrict__ selp,
                      int* __restrict__ kp, int* __restrict__ ts){
  int i = blockIdx.x*256 + threadIdx.x;
  if (i >= NN) return;
  unsigned long long sp = selp[0];
  int s = indptr[i], e = indptr[i+1];
  int self = (keys[i] <= sp) ? 1 : 0;
  kp[i] = self;
  int acc = self;
  for (int j=s;j<e;j++) acc += (keys[csr_r[j]] <= sp) ? 1 : 0;
  ts[i] = acc;
}
// pooled degree pass 2 + dinv1 MERGED with hp = (x1*score)@W1
__global__ void k_csgmm(const int* __restrict__ indptr, const int* __restrict__ csr_r,
                        const int* __restrict__ ts, const int* __restrict__ diagint,
                        const int* __restrict__ kp, float* __restrict__ dinv1,
                        const float* __restrict__ X, const float* __restrict__ W,
                        const float* __restrict__ sc, float* __restrict__ Y){
  int idx = blockIdx.x*256 + threadIdx.x;
  if (idx < NN*16){
    int i = idx>>4, fq = idx&15;
    if (!kp[i]) return;
    const vf4* X4 = (const vf4*)&X[i*64];
    const vf4* W4 = (const vf4*)W;
    vf4 acc = {0.f,0.f,0.f,0.f};
    #pragma unroll
    for (int kq=0;kq<16;kq++){
      vf4 xv = X4[kq];
      #pragma unroll
      for (int u=0;u<4;u++) acc += xv[u] * W4[(kq*4+u)*16+fq];
    }
    acc *= sc[i];
    ((vf4*)Y)[i*16+fq] = acc;
  } else {
    int i = idx - NN*16;
    if (i >= NN) return;
    int s = indptr[i], e = indptr[i+1];
    int acc = ts[i];
    for (int j=s;j<e;j++) acc += ts[csr_r[j]];
    dinv1[i] = kp[i] ? rsqrtf((float)(acc - diagint[i] - 1) + 2.0f) : 0.f;
  }
}

// ---------------- LSTM part 1: XW[n] = src[n] @ W_ih^T + (b_ih+b_hh) ----------------
__global__ __launch_bounds__(256) void k_xw(const float* __restrict__ src,
        const float* __restrict__ WT, const float* __restrict__ bsum,
        float* __restrict__ XW){
  __shared__ vf4 Wl[4096];              // 64 KB: WT[k][g] as vf4[(k*4+u)*64+fq]
  int t = threadIdx.x;
  const vf4* Wg = (const vf4*)WT;
  for (int u=t; u<4096; u+=256) Wl[u] = Wg[u];
  int fq = t & 63, wv = t >> 6;
  vf4 bias = ((const vf4*)bsum)[fq];
  __syncthreads();
  for (int g = blockIdx.x*4 + wv; g < NN/4; g += gridDim.x*4){
    int n0 = g*4;
    const vf4* X4 = (const vf4*)&src[(size_t)n0*64];   // 4 rows x 16 vf4
    vf4 a0=bias, a1=bias, a2=bias, a3=bias;
    #pragma unroll 4
    for (int kq=0;kq<16;kq++){
      vf4 x0 = X4[kq], x1 = X4[16+kq], x2 = X4[32+kq], x3 = X4[48+kq];
      vf4 w0 = Wl[(kq*4+0)*64+fq];
      vf4 w1 = Wl[(kq*4+1)*64+fq];
      vf4 w2 = Wl[(kq*4+2)*64+fq];
      vf4 w3 = Wl[(kq*4+3)*64+fq];
      a0 += x0.x*w0 + x0.y*w1 + x0.z*w2 + x0.w*w3;
      a1 += x1.x*w0 + x1.y*w1 + x1.z*w2 + x1.w*w3;
      a2 += x2.x*w0 + x2.y*w1 + x2.z*w2 + x2.w*w3;
      a3 += x3.x*w0 + x3.y*w1 + x3.z*w2 + x3.w*w3;
    }
    vf4* Y = (vf4*)XW;
    Y[(size_t)n0*64 + fq]       = a0;
    Y[(size_t)n0*64 + 64 + fq]  = a1;
    Y[(size_t)n0*64 + 128 + fq] = a2;
    Y[(size_t)n0*64 + 192 + fq] = a3;
  }
}

// ---------------- LSTM part 2: recurrence (hh-half only) ----------------
// R7-proven config: 4 nodes/block, per-wave XW-row prefetch. Grid 768 =
// exactly 3 co-resident blocks/CU x 256 CUs (register-limited occupancy);
// fewer per-block weight reloads than 1024, even 8.1 tasks/block.
// Structural floor: per timestep 64 broadcast ds_read_b128 + 256 FMA +
// 2 barriers; arithmetic matches measured ~83 us — at this decomposition's
// pipe limit (R6-R9 tried prefetch/grid/8-node: all <=+4%).
__global__ __launch_bounds__(256) void k_rec(const float* __restrict__ XW,
        const float* __restrict__ whh, const float* __restrict__ bsum,
        const int* __restrict__ mlist, const unsigned* __restrict__ scal,
        float* __restrict__ dst, int scatter){
  int M = (int)scal[0];
  if (M < 0 || M > NN) M = 0;          // defensive (rocprof replay poisons scal)
  int w = threadIdx.x>>6, lane = threadIdx.x&63;
  int r = w*64 + lane;
  const vf4* g4 = (const vf4*)&whh[(size_t)r*64];
  vf4 wh[16];
  #pragma unroll
  for (int j=0;j<16;j++) wh[j] = g4[j];
  __shared__ float sh[4][64];
  __shared__ float gates[4][4][64];
  int ntask = (M+3)>>2;
  for (int task = blockIdx.x; task < ntask; task += gridDim.x){
    int m = task*4 + w;
    bool valid = (m < M);
    int node = mlist[valid ? m : (M-1)];
    node = min(max(node, 0), NN-1);    // defensive vs poisoned mlist in replay
    float c, h;
    float x0,x1,x2,x3;
    {   // t = 0: h==0, gates = XW row (bias-only if left-padded)
      int rowi = node - (SEQL-1);
      if (rowi >= 0){
        const float* p = &XW[(size_t)rowi*256];
        x0=p[lane]; x1=p[64+lane]; x2=p[128+lane]; x3=p[192+lane];
      } else {
        x0=bsum[lane]; x1=bsum[64+lane]; x2=bsum[128+lane]; x3=bsum[192+lane];
      }
      c = sigm(x0)*ftanh(x2);
      h = sigm(x3)*ftanh(c);
      sh[w][lane] = h;
    }
    __syncthreads();
    for (int t=1;t<SEQL;t++){
      // prefetch this timestep's gate-x row (wave w -> its own node)
      int rowi = node - (SEQL-1) + t;
      if (rowi >= 0){
        const float* p = &XW[(size_t)rowi*256];
        x0=p[lane]; x1=p[64+lane]; x2=p[128+lane]; x3=p[192+lane];
      } else {
        x0=bsum[lane]; x1=bsum[64+lane]; x2=bsum[128+lane]; x3=bsum[192+lane];
      }
      vf4 a0={0,0,0,0}, a1={0,0,0,0}, a2={0,0,0,0}, a3={0,0,0,0};
      #pragma unroll
      for (int j=0;j<16;j++){
        vf4 wj = wh[j];
        a0 += (*(const vf4*)&sh[0][j*4]) * wj;
        a1 += (*(const vf4*)&sh[1][j*4]) * wj;
        a2 += (*(const vf4*)&sh[2][j*4]) * wj;
        a3 += (*(const vf4*)&sh[3][j*4]) * wj;
      }
      gates[0][w][lane] = a0.x+a0.y+a0.z+a0.w;
      gates[1][w][lane] = a1.x+a1.y+a1.z+a1.w;
      gates[2][w][lane] = a2.x+a2.y+a2.z+a2.w;
      gates[3][w][lane] = a3.x+a3.y+a3.z+a3.w;
      __syncthreads();
      float gi = gates[w][0][lane] + x0;
      float gf = gates[w][1][lane] + x1;
      float gg = gates[w][2][lane] + x2;
      float go = gates[w][3][lane] + x3;
      c = sigm(gf)*c + sigm(gi)*ftanh(gg);
      h = sigm(go)*ftanh(c);
      sh[w][lane] = h;
      __syncthreads();
    }
    if (valid){
      size_t o = scatter ? ((size_t)node*64 + lane) : ((size_t)m*64 + lane);
      dst[o] = h;
    }
  }
}

// ==========================================================================
extern "C" void kernel_launch(void* const* d_in, const int* in_sizes, int n_in,
                              void* d_out, int out_size, void* d_ws, size_t ws_size,
                              hipStream_t stream) {
  const float* x   = (const float*)d_in[0];
  const int*   ei  = (const int*)d_in[1];
  const int*   row = ei;
  const int*   col = ei + EE;
  const void*  mp  = d_in[2];
  const float* W0  = (const float*)d_in[3];
  const float* b0  = (const float*)d_in[4];
  const float* W1  = (const float*)d_in[5];
  const float* b1  = (const float*)d_in[6];
  const float* pw  = (const float*)d_in[7];
  const float* Wu  = (const float*)d_in[8];
  const float* bu  = (const float*)d_in[9];
  const float* l0wih=(const float*)d_in[10];
  const float* l0whh=(const float*)d_in[11];
  const float* l0bih=(const float*)d_in[12];
  const float* l0bhh=(const float*)d_in[13];
  const float* lfwih=(const float*)d_in[14];
  const float* lfwhh=(const float*)d_in[15];
  const float* lfbih=(const float*)d_in[16];
  const float* lfbhh=(const float*)d_in[17];

  char* wp = (char*)d_ws;
  auto alloc = [&](size_t bytes)->char*{ char* p = wp; wp += ((bytes+255)/256)*256; return p; };
  float* A     = (float*)alloc((size_t)NN*64*4);   // h0 -> t2
  float* B     = (float*)alloc((size_t)NN*64*4);   // xo
  float* C     = (float*)alloc((size_t)NN*64*4);   // x1
  float* D     = (float*)alloc((size_t)NN*64*4);   // y
  float* Ebuf  = (float*)alloc((size_t)NN*64*4);   // hp -> up-GCN input
  float* Hbuf  = (float*)alloc((size_t)NN*64*4);   // LSTM0 compact output
  float* XW    = (float*)alloc((size_t)NN*256*4);  // gate-x precompute (51.2 MB)
  float* WT0   = (float*)alloc((size_t)256*64*4);
  float* WTf   = (float*)alloc((size_t)256*64*4);
  float* bs0   = (float*)alloc((size_t)256*4);
  float* bsf   = (float*)alloc((size_t)256*4);
  float* score = (float*)alloc((size_t)NN*4);
  float* dinv0 = (float*)alloc((size_t)NN*4);
  float* dinv1 = (float*)alloc((size_t)NN*4);
  unsigned long long* keys = (unsigned long long*)alloc((size_t)NN*8);
  int* degcnt  = (int*)alloc((size_t)NN*4);
  int* diagint = (int*)alloc((size_t)NN*4);
  int* ts      = (int*)alloc((size_t)NN*4);
  int* kp      = (int*)alloc((size_t)NN*4);
  int* mlist   = (int*)alloc((size_t)NN*4);
  int* minv    = (int*)alloc((size_t)NN*4);
  int* indptr  = (int*)alloc((size_t)(NN+1)*4);
  int* part    = (int*)alloc((size_t)NN*4);
  int* fillc   = (int*)alloc((size_t)NN*4);
  int* bsum    = (int*)alloc((size_t)256*4);
  int* csr_r   = (int*)alloc((size_t)EE*4);
  uint2* hash  = (uint2*)alloc((size_t)HASH_SIZE*8);
  unsigned* hist=(unsigned*)alloc((size_t)4*65536*4);
  unsigned* scal=(unsigned*)alloc(256);
  unsigned long long* selp = (unsigned long long*)(scal + 4);

  #define GRID1(n) dim3(((n)+255)/256), dim3(256), 0, stream
  #define GRIDW dim3((NN+3)/4), dim3(256), 0, stream

  // 1. merged init (hash, hist, per-node arrays, scalars, LSTM weight prep)
  k_init<<<GRID1(HASH_SIZE)>>>(hash, hist, degcnt, diagint, fillc, minv,
                               scal, selp, l0wih, l0bih, l0bhh, lfwih, lfbih, lfbhh,
                               WT0, WTf, bs0, bsf);
  // 2. degcnt + hash build + mask detect + GCN0 matmul (merged)
  k_phase2<<<GRID1(NN*16)>>>(row, col, (const int*)mp, degcnt, hash, scal, x, W0, A);
  // 3-4. indptr prefix sum (+dinv0); psum3 self-computes block offsets
  k_psum1<<<dim3(PSB),dim3(256),0,stream>>>(degcnt, part, bsum, dinv0);
  k_psum3<<<dim3(PSB),dim3(256),0,stream>>>(part, bsum, indptr);
  // 5. csr fill + A^2 diag + mask compact
  k_phase4<<<GRID1(EE+NN)>>>(row, col, indptr, fillc, csr_r, hash, diagint, mp, scal, mlist, minv);

  // GCN0 gather (+ fused TopK score/key + radix round-0 hist)
  g_gcn0<<<GRIDW>>>(indptr, csr_r, dinv0, A, b0, pw, C, keys, score, hist);

  // TopK radix select: all 4 rounds fused into one single-block kernel
  k_radix<<<dim3(1),dim3(256),0,stream>>>(keys, hist, selp, scal);

  // pooled degree pass 1, then pass2+dinv1 merged with hp matmul
  k_tsg<<<GRID1(NN)>>>(indptr, csr_r, keys, selp, kp, ts);
  k_csgmm<<<GRID1(NN*16+NN)>>>(indptr, csr_r, ts, diagint, kp, dinv1, C, W1, score, Ebuf);
  g_t2<<<GRIDW>>>(indptr, csr_r, dinv1, Ebuf, A);

  // LSTM0 on x1 windows -> Hbuf (compact)
  k_xw<<<dim3(512),dim3(256),0,stream>>>(C, WT0, bs0, XW);
  k_rec<<<dim3(768),dim3(256),0,stream>>>(XW, l0whh, bs0, mlist, scal, Hbuf, 0);

  // y = res + up (fused: base select + relu(x2))
  g_agg2y<<<GRIDW>>>(indptr, csr_r, A, Ebuf, dinv1, diagint, kp, b1, C, Hbuf, minv, D);

  // up-GCN -> xo (B) and d_out
  k_mm64v<<<GRID1(NN*16)>>>(D, Wu, Ebuf);
  g_up<<<GRIDW>>>(indptr, csr_r, dinv0, Ebuf, bu, B, (float*)d_out);

  // final LSTM on xo windows, scatter into d_out masked rows
  k_xw<<<dim3(512),dim3(256),0,stream>>>(B, WTf, bsf, XW);
  k_rec<<<dim3(768),dim3(256),0,stream>>>(XW, lfwhh, bsf, mlist, scal, (float*)d_out, 1);
  #undef GRIDW
  #undef GRID1
}